// Round 1
// baseline (236.385 us; speedup 1.0000x reference)
//
#include <hip/hip_runtime.h>
#include <math.h>

#define HDIM 256
#define H4   64          // HDIM / 4
#define EPSN 1e-8f       // torch F.cosine_similarity norm clamp

// ---------------------------------------------------------------------------
// Kernel 0: detect storage layout of is_compressed (deterministic from data).
// flag: 0 = int32 per element, 1 = 1-byte per element (np.bool_/int8),
//       2 = float32 per element.
// Scanning only the first C BYTES is safe under every candidate layout.
// int32 layout: bytes at i%4!=0 are all zero (values are 0/1).
// byte  layout: random 0/1 bytes everywhere, none >1.
// float layout: true = 0x3F800000 -> bytes 0x80/0x3F (>1) appear.
// ---------------------------------------------------------------------------
__global__ void detect_mask_layout(const unsigned char* __restrict__ m, int C,
                                   int* __restrict__ flag) {
    __shared__ int f_off, f_gt1;
    if (threadIdx.x == 0) { f_off = 0; f_gt1 = 0; }
    __syncthreads();
    int loc_off = 0, loc_gt1 = 0;
    for (int i = threadIdx.x; i < C; i += blockDim.x) {
        unsigned char v = m[i];
        if (v > 1) loc_gt1 = 1;
        if ((i & 3) != 0 && v != 0) loc_off = 1;
    }
    if (loc_off) atomicOr(&f_off, 1);
    if (loc_gt1) atomicOr(&f_gt1, 1);
    __syncthreads();
    if (threadIdx.x == 0) *flag = f_gt1 ? 2 : (f_off ? 1 : 0);
}

// ---------------------------------------------------------------------------
// Kernel 1: sims[b][c] = cos(query_b, emb_c) with per-norm eps clamping.
// Block = 256 threads (4 waves). Each block: 64 consecutive c x all 64 b.
// e-chunk staged in LDS (64 KB) with f4-index XOR swizzle (i ^ (c&7)) so the
// hot ds_read_b128 is same-address-broadcast per 8-lane group (conflict-free).
// Each wave: lane <-> c, 16 b's with 16-wide accumulator blocking.
// ---------------------------------------------------------------------------
__global__ __launch_bounds__(256)
void sims_kernel(const float* __restrict__ query,   // [B=64][256]
                 const float* __restrict__ emb,     // [C][256]
                 float* __restrict__ sims,          // [B][C]
                 int C) {
    __shared__ float4 lds_e[64][H4];    // exactly 64 KB

    const int t    = threadIdx.x;
    const int lane = t & 63;
    const int w    = t >> 6;
    const int c0   = blockIdx.x * 64;

    // ---- stage e-chunk (coalesced float4, zero-fill OOB) ----
    const float4* emb4 = (const float4*)emb;
    for (int idx = t; idx < 64 * H4; idx += 256) {
        int cl = idx >> 6;          // row (local c), uniform per wave-iter
        int i  = idx & 63;          // f4 column = lane
        int c  = c0 + cl;
        float4 v = make_float4(0.f, 0.f, 0.f, 0.f);
        if (c < C) v = emb4[(size_t)c * H4 + i];
        lds_e[cl][i ^ (cl & 7)] = v;
    }
    __syncthreads();

    const int s = lane & 7;

    // ---- per-lane e-norm from staged LDS row ----
    float ee = 0.f;
    #pragma unroll
    for (int i = 0; i < H4; ++i) {
        float4 e4 = lds_e[lane][i ^ s];
        ee = fmaf(e4.x, e4.x, fmaf(e4.y, e4.y, fmaf(e4.z, e4.z, fmaf(e4.w, e4.w, ee))));
    }
    const float inv_en = 1.f / fmaxf(sqrtf(ee), EPSN);

    // ---- per-b q-norms (uniform per wave) via 64-lane butterfly ----
    const float4* q4p = (const float4*)query;
    float invq[16];
    #pragma unroll
    for (int bi = 0; bi < 16; ++bi) {
        int b = w * 16 + bi;
        float4 v = q4p[(size_t)b * H4 + lane];
        float ss = fmaf(v.x, v.x, fmaf(v.y, v.y, fmaf(v.z, v.z, v.w * v.w)));
        #pragma unroll
        for (int off = 32; off; off >>= 1) ss += __shfl_xor(ss, off, 64);
        invq[bi] = 1.f / fmaxf(sqrtf(ss), EPSN);
    }

    // ---- main: 16-wide b-blocking, one LDS read feeds 64 FMAs ----
    float acc[16];
    #pragma unroll
    for (int bi = 0; bi < 16; ++bi) acc[bi] = 0.f;

    for (int i = 0; i < H4; ++i) {
        float4 e4 = lds_e[lane][i ^ s];
        #pragma unroll
        for (int bi = 0; bi < 16; ++bi) {
            int b = w * 16 + bi;
            float4 q = q4p[(size_t)b * H4 + i];   // uniform address -> broadcast
            acc[bi] = fmaf(q.x, e4.x, fmaf(q.y, e4.y,
                       fmaf(q.z, e4.z, fmaf(q.w, e4.w, acc[bi]))));
        }
    }

    const int c = c0 + lane;
    if (c < C) {
        #pragma unroll
        for (int bi = 0; bi < 16; ++bi) {
            int b = w * 16 + bi;
            sims[(size_t)b * C + c] = acc[bi] * invq[bi] * inv_en;   // coalesced
        }
    }
}

// ---------------------------------------------------------------------------
// Kernel 2: per-row top-8 (descending, lower index wins ties — lax.top_k).
// One block per b. Thread-local sorted top-8 over strided c, then 8 rounds of
// block-wide argmax with consumed-entry marking.
// ---------------------------------------------------------------------------
__global__ __launch_bounds__(256)
void topk_kernel(const float* __restrict__ sims,   // [B][C]
                 float* __restrict__ scores_out,   // [B][8]
                 int* __restrict__ idx_out,        // [B][8]
                 int C) {
    __shared__ float sh_s[2048];
    __shared__ int   sh_i[2048];
    __shared__ float red_s[256];
    __shared__ int   red_i[256];
    __shared__ int   red_slot[256];

    const int b = blockIdx.x;
    const int t = threadIdx.x;
    const float* row = sims + (size_t)b * C;

    float ls[8]; int li[8];
    #pragma unroll
    for (int j = 0; j < 8; ++j) { ls[j] = -INFINITY; li[j] = 0x7fffffff; }

    for (int c = t; c < C; c += 256) {
        float v = row[c];
        if (v > ls[7] || (v == ls[7] && c < li[7])) {
            ls[7] = v; li[7] = c;
            #pragma unroll
            for (int j = 7; j > 0; --j) {
                bool sw = (ls[j] > ls[j-1]) || (ls[j] == ls[j-1] && li[j] < li[j-1]);
                if (sw) {
                    float tv = ls[j]; ls[j] = ls[j-1]; ls[j-1] = tv;
                    int   ti = li[j]; li[j] = li[j-1]; li[j-1] = ti;
                }
            }
        }
    }
    #pragma unroll
    for (int j = 0; j < 8; ++j) { sh_s[t*8+j] = ls[j]; sh_i[t*8+j] = li[j]; }
    __syncthreads();

    for (int r = 0; r < 8; ++r) {
        float bs = -INFINITY; int bi = 0x7fffffff; int bslot = 0;
        #pragma unroll
        for (int j = 0; j < 8; ++j) {
            float v = sh_s[t*8+j]; int ii = sh_i[t*8+j];
            if (v > bs || (v == bs && ii < bi)) { bs = v; bi = ii; bslot = t*8+j; }
        }
        red_s[t] = bs; red_i[t] = bi; red_slot[t] = bslot;
        __syncthreads();
        for (int off = 128; off > 0; off >>= 1) {
            if (t < off) {
                float v = red_s[t+off]; int ii = red_i[t+off];
                if (v > red_s[t] || (v == red_s[t] && ii < red_i[t])) {
                    red_s[t] = v; red_i[t] = ii; red_slot[t] = red_slot[t+off];
                }
            }
            __syncthreads();
        }
        if (t == 0) {
            scores_out[b*8 + r] = red_s[0];
            idx_out[b*8 + r]    = red_i[0];
            sh_s[red_slot[0]] = -INFINITY;
            sh_i[red_slot[0]] = 0x7fffffff;
        }
        __syncthreads();
    }
}

// ---------------------------------------------------------------------------
// Kernel 3: gather. One block per (b, j): copy full episode OR
// compressed episode + zero padding, float4-vectorized.
// ---------------------------------------------------------------------------
__global__ __launch_bounds__(256)
void gather_kernel(const float* __restrict__ episodes,    // [C][S][256]
                   const float* __restrict__ compressed,  // [C][Cs][256]
                   const void* __restrict__ is_comp,
                   const int* __restrict__ top_idx,       // [B*8]
                   const int* __restrict__ layout_flag,
                   float* __restrict__ out,               // [B*8][S*256]
                   int S, int Cs) {
    const int bj  = blockIdx.x;
    const int idx = top_idx[bj];
    const int fl  = *layout_flag;

    bool comp;
    if      (fl == 1) comp = ((const unsigned char*)is_comp)[idx] != 0;
    else if (fl == 2) comp = ((const float*)is_comp)[idx] != 0.f;
    else              comp = ((const int*)is_comp)[idx] != 0;

    const int n4 = S * H4;      // 2048
    const int c4 = Cs * H4;     // 1024
    const float4* full4 = (const float4*)episodes   + (size_t)idx * n4;
    const float4* cmp4  = (const float4*)compressed + (size_t)idx * c4;
    float4* out4 = (float4*)out + (size_t)bj * n4;
    const float4 z = make_float4(0.f, 0.f, 0.f, 0.f);

    for (int v = threadIdx.x; v < n4; v += blockDim.x) {
        float4 val;
        if (comp) val = (v < c4) ? cmp4[v] : z;
        else      val = full4[v];
        out4[v] = val;
    }
}

// ---------------------------------------------------------------------------
extern "C" void kernel_launch(void* const* d_in, const int* in_sizes, int n_in,
                              void* d_out, int out_size, void* d_ws, size_t ws_size,
                              hipStream_t stream) {
    const float* query      = (const float*)d_in[0];
    const float* episodes   = (const float*)d_in[1];
    const float* compressed = (const float*)d_in[2];
    const float* emb        = (const float*)d_in[3];
    const void*  is_comp    = d_in[4];
    // d_in[5] is k (device scalar); fixed at 8 by the problem setup.

    const int B  = in_sizes[0] / HDIM;        // 64
    const int C  = in_sizes[3] / HDIM;        // 20000
    const int S  = in_sizes[1] / (C * HDIM);  // 32
    const int Cs = in_sizes[2] / (C * HDIM);  // 16
    const int K  = 8;

    float* out        = (float*)d_out;
    float* scores_out = out + (size_t)B * K * S * HDIM;

    // sims scratch lives in the retrieved-output region of d_out (5.12 MB of
    // 16.8 MB); it is fully consumed by topk before gather overwrites it.
    float* sims = out;

    int* top_idx = (int*)d_ws;          // B*K ints
    int* flag    = top_idx + B * K;     // 1 int  (total ws use: 2052 B)

    detect_mask_layout<<<1, 256, 0, stream>>>((const unsigned char*)is_comp, C, flag);
    sims_kernel<<<(C + 63) / 64, 256, 0, stream>>>(query, emb, sims, C);
    topk_kernel<<<B, 256, 0, stream>>>(sims, scores_out, top_idx, C);
    gather_kernel<<<B * K, 256, 0, stream>>>(episodes, compressed, is_comp,
                                             top_idx, flag, out, S, Cs);
}

// Round 2
// 89.442 us; speedup vs baseline: 2.6429x; 2.6429x over previous
//
#include <hip/hip_runtime.h>
#include <math.h>

#define HDIM 256
#define H4   64          // HDIM / 4
#define EPSN 1e-8f       // torch F.cosine_similarity norm clamp

typedef unsigned long long u64;
typedef unsigned int       u32;

// Monotonic (value, index) packing: larger key == better candidate under
// lax.top_k semantics (descending value, lower index wins ties).
__device__ __forceinline__ u64 make_key(float v, int idx) {
    u32 u = __float_as_uint(v);
    u ^= (u & 0x80000000u) ? 0xFFFFFFFFu : 0x80000000u;   // order-preserving map
    return ((u64)u << 32) | (u32)(~idx);
}
__device__ __forceinline__ float key_val(u64 k) {
    u32 u = (u32)(k >> 32);
    u ^= (u & 0x80000000u) ? 0x80000000u : 0xFFFFFFFFu;   // inverse map
    return __uint_as_float(u);
}
__device__ __forceinline__ int key_idx(u64 k) { return (int)(~(u32)k); }

// ---------------------------------------------------------------------------
// Kernel 0: detect storage layout of is_compressed (deterministic from data).
// flags[0]=f_off (nonzero byte at i%4!=0 -> 1-byte layout),
// flags[1]=f_gt1 (any byte>1 -> float32 layout). Neither -> int32 layout.
// Vectorized u32 scan: 5000 loads over 1024 threads, all independent.
// ---------------------------------------------------------------------------
__global__ void detect_mask_layout(const u32* __restrict__ m4, int C,
                                   int* __restrict__ flags) {
    __shared__ int f_off, f_gt1;
    if (threadIdx.x == 0) { f_off = 0; f_gt1 = 0; }
    __syncthreads();
    const int n4 = C >> 2;
    int lo = 0, lg = 0;
    for (int i = threadIdx.x; i < n4; i += blockDim.x) {
        u32 v = m4[i];
        if (v & 0xFFFFFF00u) lo = 1;   // any nonzero byte at offset 1..3
        if (v & 0xFEFEFEFEu) lg = 1;   // any byte value > 1
    }
    const unsigned char* mb = (const unsigned char*)m4;
    for (int i = (n4 << 2) + threadIdx.x; i < C; i += blockDim.x) {
        unsigned char v = mb[i];
        if (v > 1) lg = 1;
        if ((i & 3) != 0 && v != 0) lo = 1;
    }
    if (lo) atomicOr(&f_off, 1);
    if (lg) atomicOr(&f_gt1, 1);
    __syncthreads();
    if (threadIdx.x == 0) { flags[0] = f_off; flags[1] = f_gt1; }
}

// ---------------------------------------------------------------------------
// Kernel 1: sims[b][c] = cos(query_b, emb_c), eps-clamped norms.
// 32x32 two-tile LDS GEMM: e-tile (32 c, XOR-swizzled cols) + q-tile (32 b)
// = exactly 64 KB static LDS -> 2 blocks/CU. Main loop touches LDS only.
// Block 256 = 4 waves; lane: cl = lane&31 (c), bq = lane>>5; each lane owns
// 4 b's (bb = w*8+bq*4). e-norm fused into the dot loop; q-norms via one
// 8-row butterfly per wave (kept in registers, no extra LDS).
// ---------------------------------------------------------------------------
__global__ __launch_bounds__(256)
void sims_kernel(const float4* __restrict__ q4,
                 const float4* __restrict__ emb4,
                 float* __restrict__ sims, int C, int B) {
    __shared__ float4 lds_e[32][H4];   // 32 KB, col ^= (row&7)
    __shared__ float4 lds_q[32][H4];   // 32 KB, linear

    const int t    = threadIdx.x;
    const int lane = t & 63;
    const int w    = t >> 6;
    const int c0   = blockIdx.x * 32;
    const int b0   = blockIdx.y * 32;

    // stage both tiles (2048 f4 each, coalesced, zero-fill OOB)
    for (int idx = t; idx < 32 * H4; idx += 256) {
        int r = idx >> 6, i = idx & 63;
        float4 ev = make_float4(0.f, 0.f, 0.f, 0.f);
        float4 qv = make_float4(0.f, 0.f, 0.f, 0.f);
        if (c0 + r < C) ev = emb4[(size_t)(c0 + r) * H4 + i];
        if (b0 + r < B) qv = q4[(size_t)(b0 + r) * H4 + i];
        lds_e[r][i ^ (r & 7)] = ev;
        lds_q[r][i]           = qv;
    }
    __syncthreads();

    // q inv-norms for this wave's 8 local b rows [w*8, w*8+8)
    float qinv[8];
    #pragma unroll
    for (int bi = 0; bi < 8; ++bi) {
        float4 v = lds_q[w * 8 + bi][lane];
        float ss = fmaf(v.x, v.x, fmaf(v.y, v.y, fmaf(v.z, v.z, v.w * v.w)));
        #pragma unroll
        for (int off = 32; off; off >>= 1) ss += __shfl_xor(ss, off, 64);
        qinv[bi] = 1.f / fmaxf(sqrtf(ss), EPSN);
    }

    const int cl = lane & 31;
    const int bq = lane >> 5;
    const int bb = w * 8 + bq * 4;    // 4 local b's: bb..bb+3
    const int s  = cl & 7;

    float a0 = 0.f, a1 = 0.f, a2 = 0.f, a3 = 0.f, ee = 0.f;
    for (int i = 0; i < H4; ++i) {
        float4 e  = lds_e[cl][i ^ s];                 // 32 distinct addrs, conflict-balanced
        float4 p0 = lds_q[bb + 0][i];                 // 2 distinct addrs -> broadcast
        float4 p1 = lds_q[bb + 1][i];
        float4 p2 = lds_q[bb + 2][i];
        float4 p3 = lds_q[bb + 3][i];
        ee = fmaf(e.x, e.x, fmaf(e.y, e.y, fmaf(e.z, e.z, fmaf(e.w, e.w, ee))));
        a0 = fmaf(p0.x, e.x, fmaf(p0.y, e.y, fmaf(p0.z, e.z, fmaf(p0.w, e.w, a0))));
        a1 = fmaf(p1.x, e.x, fmaf(p1.y, e.y, fmaf(p1.z, e.z, fmaf(p1.w, e.w, a1))));
        a2 = fmaf(p2.x, e.x, fmaf(p2.y, e.y, fmaf(p2.z, e.z, fmaf(p2.w, e.w, a2))));
        a3 = fmaf(p3.x, e.x, fmaf(p3.y, e.y, fmaf(p3.z, e.z, fmaf(p3.w, e.w, a3))));
    }
    const float einv = 1.f / fmaxf(sqrtf(ee), EPSN);

    const int c = c0 + cl;
    if (c < C) {
        float q0 = bq ? qinv[4] : qinv[0];   // compile-time reg indices + cndmask
        float q1 = bq ? qinv[5] : qinv[1];
        float q2 = bq ? qinv[6] : qinv[2];
        float q3 = bq ? qinv[7] : qinv[3];
        size_t base = (size_t)(b0 + bb) * C + c;
        if (b0 + bb + 0 < B) sims[base]               = a0 * q0 * einv;
        if (b0 + bb + 1 < B) sims[base + (size_t)C]   = a1 * q1 * einv;
        if (b0 + bb + 2 < B) sims[base + 2*(size_t)C] = a2 * q2 * einv;
        if (b0 + bb + 3 < B) sims[base + 3*(size_t)C] = a3 * q3 * einv;
    }
}

// ---------------------------------------------------------------------------
// Kernel 2: per-row top-8 via u64 keys. One block per b.
// Phase 1: per-thread sorted top-8 over strided scan (coalesced).
// Phase 2 (single barrier): wave 0 merges 2048 candidates -> 8 rounds of
// 64-lane shfl-butterfly argmax (keys unique, exactly one owner pops).
// ---------------------------------------------------------------------------
__global__ __launch_bounds__(256)
void topk_kernel(const float* __restrict__ sims,
                 float* __restrict__ scores_out,
                 int* __restrict__ idx_out, int C) {
    __shared__ u64 sh[256 * 8];   // 16 KB
    const int b = blockIdx.x, t = threadIdx.x;
    const float* row = sims + (size_t)b * C;

    u64 ls[8];
    #pragma unroll
    for (int j = 0; j < 8; ++j) ls[j] = 0ull;

    for (int c = t; c < C; c += 256) {
        u64 k = make_key(row[c], c);
        if (k > ls[7]) {
            ls[7] = k;
            #pragma unroll
            for (int j = 7; j > 0; --j)
                if (ls[j] > ls[j-1]) { u64 tmp = ls[j]; ls[j] = ls[j-1]; ls[j-1] = tmp; }
        }
    }
    #pragma unroll
    for (int j = 0; j < 8; ++j) sh[t * 8 + j] = ls[j];
    __syncthreads();

    if (t < 64) {
        u64 m[8];
        #pragma unroll
        for (int j = 0; j < 8; ++j) m[j] = 0ull;
        for (int tt = 0; tt < 4; ++tt) {
            const u64* p = &sh[(t * 4 + tt) * 8];
            #pragma unroll
            for (int j = 0; j < 8; ++j) {
                u64 k = p[j];
                if (k <= m[7]) break;           // p[] sorted descending
                m[7] = k;
                #pragma unroll
                for (int q = 7; q > 0; --q)
                    if (m[q] > m[q-1]) { u64 tmp = m[q]; m[q] = m[q-1]; m[q-1] = tmp; }
            }
        }
        for (int r = 0; r < 8; ++r) {
            u64 best = m[0];
            #pragma unroll
            for (int off = 32; off; off >>= 1) {
                u64 o = __shfl_xor(best, off, 64);
                if (o > best) best = o;
            }
            if (m[0] == best) {                 // unique owner pops
                #pragma unroll
                for (int q = 0; q < 7; ++q) m[q] = m[q+1];
                m[7] = 0ull;
            }
            if (t == 0) {
                scores_out[b * 8 + r] = key_val(best);
                idx_out[b * 8 + r]    = key_idx(best);
            }
        }
    }
}

// ---------------------------------------------------------------------------
// Kernel 3: gather. One block per (b, j): full episode OR compressed+pad.
// ---------------------------------------------------------------------------
__global__ __launch_bounds__(256)
void gather_kernel(const float* __restrict__ episodes,    // [C][S][256]
                   const float* __restrict__ compressed,  // [C][Cs][256]
                   const void* __restrict__ is_comp,
                   const int* __restrict__ top_idx,       // [B*8]
                   const int* __restrict__ flags,
                   float* __restrict__ out,               // [B*8][S*256]
                   int S, int Cs) {
    const int bj  = blockIdx.x;
    const int idx = top_idx[bj];
    const int f_off = flags[0], f_gt1 = flags[1];

    bool comp;
    if      (f_gt1) comp = ((const float*)is_comp)[idx] != 0.f;
    else if (f_off) comp = ((const unsigned char*)is_comp)[idx] != 0;
    else            comp = ((const int*)is_comp)[idx] != 0;

    const int n4 = S * H4;      // 2048
    const int c4 = Cs * H4;     // 1024
    const float4* full4 = (const float4*)episodes   + (size_t)idx * n4;
    const float4* cmp4  = (const float4*)compressed + (size_t)idx * c4;
    float4* out4 = (float4*)out + (size_t)bj * n4;
    const float4 z = make_float4(0.f, 0.f, 0.f, 0.f);

    if (comp) {
        for (int v = threadIdx.x; v < n4; v += blockDim.x)
            out4[v] = (v < c4) ? cmp4[v] : z;
    } else {
        for (int v = threadIdx.x; v < n4; v += blockDim.x)
            out4[v] = full4[v];
    }
}

// ---------------------------------------------------------------------------
extern "C" void kernel_launch(void* const* d_in, const int* in_sizes, int n_in,
                              void* d_out, int out_size, void* d_ws, size_t ws_size,
                              hipStream_t stream) {
    const float* query      = (const float*)d_in[0];
    const float* episodes   = (const float*)d_in[1];
    const float* compressed = (const float*)d_in[2];
    const float* emb        = (const float*)d_in[3];
    const void*  is_comp    = d_in[4];
    // d_in[5] is k (device scalar); fixed at 8 by the problem setup.

    const int B  = in_sizes[0] / HDIM;        // 64
    const int C  = in_sizes[3] / HDIM;        // 20000
    const int S  = in_sizes[1] / (C * HDIM);  // 32
    const int Cs = in_sizes[2] / (C * HDIM);  // 16
    const int K  = 8;

    float* out        = (float*)d_out;
    float* scores_out = out + (size_t)B * K * S * HDIM;

    // sims scratch lives in the retrieved-output region of d_out (5.12 MB of
    // 16.8 MB); fully consumed by topk before gather overwrites it.
    float* sims = out;

    int* top_idx = (int*)d_ws;          // B*K ints
    int* flags   = top_idx + B * K;     // 2 ints

    detect_mask_layout<<<1, 1024, 0, stream>>>((const u32*)is_comp, C, flags);
    sims_kernel<<<dim3((C + 31) / 32, (B + 31) / 32), 256, 0, stream>>>(
        (const float4*)query, (const float4*)emb, sims, C, B);
    topk_kernel<<<B, 256, 0, stream>>>(sims, scores_out, top_idx, C);
    gather_kernel<<<B * K, 256, 0, stream>>>(episodes, compressed, is_comp,
                                             top_idx, flags, out, S, Cs);
}